// Round 6
// baseline (111.815 us; speedup 1.0000x reference)
//
#include <hip/hip_runtime.h>
#include <math.h>

#define BB 4
#define HH 128
#define WW 128
#define CIN 64
#define COUT 64
#define KK 9
#define OMC 27
#define NPIX (BB * HH * WW)

typedef __attribute__((ext_vector_type(8))) short bf16x8;
typedef __attribute__((ext_vector_type(4))) float f32x4;

static __device__ __forceinline__ unsigned short f2bf(float f) {
    unsigned int u = __float_as_uint(f);
    unsigned int r = (u + 0x7fffu + ((u >> 16) & 1u)) >> 16;
    return (unsigned short)r;
}

static __device__ __forceinline__ unsigned int pk2(float a, float b) {
    return (unsigned int)f2bf(a) | ((unsigned int)f2bf(b) << 16);
}

// ---------------------------------------------------------------------------
// Kernel 0: one-shot transform of wmain f32 [576 k][64 n] into bf16 MFMA
// B-frag-ready layout (16B/lane coalesced loads in the main kernel).
// ---------------------------------------------------------------------------
__global__ __launch_bounds__(64) void wb_transform(
    const float* __restrict__ wmain, uint4* __restrict__ wb)
{
    const int tid  = blockIdx.x * 64 + threadIdx.x;  // [0, 18*4*64)
    const int lane = tid & 63;
    const int nf   = (tid >> 6) & 3;
    const int ks   = tid >> 8;
    const int k0   = ks * 32 + ((lane >> 4) * 8);
    const int n    = nf * 16 + (lane & 15);
    unsigned short v[8];
    #pragma unroll
    for (int j = 0; j < 8; ++j) v[j] = f2bf(wmain[(size_t)(k0 + j) * COUT + n]);
    uint4 q;
    q.x = (unsigned int)v[0] | ((unsigned int)v[1] << 16);
    q.y = (unsigned int)v[2] | ((unsigned int)v[3] << 16);
    q.z = (unsigned int)v[4] | ((unsigned int)v[5] << 16);
    q.w = (unsigned int)v[6] | ((unsigned int)v[7] << 16);
    wb[tid] = q;
}

// ---------------------------------------------------------------------------
// Kernel 1: offset/mask conv as bf16 MFMA implicit GEMM.  Epilogue fuses the
// deformable prep: j<18 -> absolute sampling coords, j>=18 -> sigmoid(mask).
// ---------------------------------------------------------------------------
__global__ __launch_bounds__(256) void offset_conv_mfma(
    const float* __restrict__ x,
    const float* __restrict__ wofs,
    const float* __restrict__ bofs,
    float* __restrict__ om)
{
    __shared__ char lds[16384 + 36864];
    char* xs = lds;
    char* ws = lds + 16384;

    const int tid  = threadIdx.x;
    const int lane = tid & 63;
    const int wv   = tid >> 6;
    const int bid = ((blockIdx.x & 7) << 6) + (blockIdx.x >> 3);  // XCD chunk
    const int b = bid >> 7;
    const int h = bid & (HH - 1);
    const float* xrow0 = x + (size_t)b * HH * WW * CIN;

    #pragma unroll
    for (int r = 0; r < 9; ++r) {
        const int t  = r;
        const int j  = (tid >> 3) & 31;
        const int c8 = tid & 7;
        unsigned short v[8];
        if (j < OMC) {
            const float* wp = wofs + ((size_t)t * CIN + c8 * 8) * OMC + j;
            #pragma unroll
            for (int i = 0; i < 8; ++i) v[i] = f2bf(wp[i * OMC]);
        } else {
            #pragma unroll
            for (int i = 0; i < 8; ++i) v[i] = 0;
        }
        uint4 q;
        q.x = (unsigned int)v[0] | ((unsigned int)v[1] << 16);
        q.y = (unsigned int)v[2] | ((unsigned int)v[3] << 16);
        q.z = (unsigned int)v[4] | ((unsigned int)v[5] << 16);
        q.w = (unsigned int)v[6] | ((unsigned int)v[7] << 16);
        const int off = (((t * 32 + j) * 128) + c8 * 16) ^ ((j & 7) << 4);
        *(uint4*)(ws + off) = q;
    }

    f32x4 acc[2][2] = {};
    const int w0 = wv * 32;

    for (int ty = 0; ty < 3; ++ty) {
        const int hy = h - 1 + ty;
        const bool vrow = (hy >= 0) && (hy < HH);
        __syncthreads();
        if (vrow) {
            const float* src = xrow0 + (size_t)hy * WW * CIN;
            #pragma unroll
            for (int r = 0; r < 4; ++r) {
                const int ch = tid + 256 * r;
                const int c8 = ch & 7;
                const int w  = ch >> 3;
                const float* p = src + (size_t)w * CIN + c8 * 8;
                float4 a0 = *(const float4*)p;
                float4 a1 = *(const float4*)(p + 4);
                uint4 q;
                q.x = pk2(a0.x, a0.y);
                q.y = pk2(a0.z, a0.w);
                q.z = pk2(a1.x, a1.y);
                q.w = pk2(a1.z, a1.w);
                const int off = (w * 128 + c8 * 16) ^ ((w & 7) << 4);
                *(uint4*)(xs + off) = q;
            }
        }
        __syncthreads();
        if (!vrow) continue;

        #pragma unroll
        for (int tx = 0; tx < 3; ++tx) {
            const int t = ty * 3 + tx;
            #pragma unroll
            for (int ch2 = 0; ch2 < 2; ++ch2) {
                bf16x8 bfr[2];
                #pragma unroll
                for (int nf = 0; nf < 2; ++nf) {
                    const int j = nf * 16 + (lane & 15);
                    const int off = (((t * 32 + j) * 128) + ch2 * 64 + ((lane >> 4) * 16))
                                    ^ ((j & 7) << 4);
                    bfr[nf] = *(const bf16x8*)(ws + off);
                }
                bf16x8 afr[2];
                #pragma unroll
                for (int m = 0; m < 2; ++m) {
                    const int wp = w0 + m * 16 + (lane & 15) + tx - 1;
                    const bool vv = (wp >= 0) && (wp < WW);
                    const int wc = vv ? wp : 0;
                    const int off = (wc * 128 + ch2 * 64 + ((lane >> 4) * 16))
                                    ^ ((wc & 7) << 4);
                    bf16x8 a = *(const bf16x8*)(xs + off);
                    if (!vv) a = (bf16x8)(short)0;
                    afr[m] = a;
                }
                acc[0][0] = __builtin_amdgcn_mfma_f32_16x16x32_bf16(afr[0], bfr[0], acc[0][0], 0, 0, 0);
                acc[0][1] = __builtin_amdgcn_mfma_f32_16x16x32_bf16(afr[0], bfr[1], acc[0][1], 0, 0, 0);
                acc[1][0] = __builtin_amdgcn_mfma_f32_16x16x32_bf16(afr[1], bfr[0], acc[1][0], 0, 0, 0);
                acc[1][1] = __builtin_amdgcn_mfma_f32_16x16x32_bf16(afr[1], bfr[1], acc[1][1], 0, 0, 0);
            }
        }
    }

    const int pixbase = (b * HH + h) * WW;
    #pragma unroll
    for (int nf = 0; nf < 2; ++nf) {
        const int j = nf * 16 + (lane & 15);
        if (j >= OMC) continue;
        const float bb = bofs[j];
        #pragma unroll
        for (int m = 0; m < 2; ++m) {
            const int row0 = w0 + m * 16 + ((lane >> 4) * 4);
            #pragma unroll
            for (int r = 0; r < 4; ++r) {
                float val = acc[m][nf][r] + bb;
                const int wpix = row0 + r;
                if (j < 18) {
                    const int t = j >> 1;
                    if ((j & 1) == 0) val += (float)(h - 1 + t / 3);     // absolute py
                    else              val += (float)(wpix - 1 + t % 3);  // absolute px
                } else {
                    val = 1.0f / (1.0f + __expf(-val));                  // sigmoid(mask)
                }
                om[(size_t)(pixbase + wpix) * OMC + j] = val;
            }
        }
    }
}

// ---------------------------------------------------------------------------
// Kernel 2: deformable sampling + MFMA, register-direct A-fragments with
// 2-way K-SPLIT across a wave pair (occupancy 16 -> 32 waves/CU).
// Block = 256 thr = 4 waves = 2 pairs; each pair owns 16 pixels.
// Wave kw=0 of a pair: taps 0-4; wave kw=1: taps 5-8.  Pair reduction via
// LDS (contiguous f32x4 per lane -> conflict-free), one __syncthreads.
// Lane l: pixel p = l&15, channel group cg = l>>4.  Per tap: 16 clamped
// unconditional float4 gathers (OOB killed via zeroed bilinear weight),
// 64 FMA, pack -> 2 A-frags -> 8 MFMA (B coalesced from wb/L2).
// ---------------------------------------------------------------------------
#define TMB 32   // pixels per block

__global__ __launch_bounds__(256, 8) void dcn_main_mfma(
    const float* __restrict__ x,
    const uint4* __restrict__ wb,
    const float* __restrict__ bias,
    const float* __restrict__ om,
    float* __restrict__ out)
{
    __shared__ float om_s[2][432];    // 3456 B (per pair; duplicate-written)
    __shared__ f32x4 red[2][256];     // 8192 B pair-reduction buffer

    const int tid  = threadIdx.x;
    const int lane = tid & 63;
    const int wv   = tid >> 6;
    const int pair = wv >> 1;
    const int kw   = wv & 1;
    const int bid  = ((blockIdx.x & 7) << 8) + (blockIdx.x >> 3);  // XCD chunk (2048 = 8*256)
    const int pix0 = bid * TMB;
    const int b    = pix0 >> 14;
    const float* xb = x + (size_t)b * HH * WW * CIN;

    // ---- each wave stages its pair's om slice (432 contiguous f32).
    //      Both waves of a pair write identical values: benign, no barrier.
    float* omw = om_s[pair];
    {
        const float* og = om + (size_t)(pix0 + pair * 16) * OMC;
        #pragma unroll
        for (int i = 0; i < 7; ++i) {
            const int idx = i * 64 + lane;
            if (idx < 432) omw[idx] = og[idx];
        }
    }

    const int p  = lane & 15;
    const int cg = lane >> 4;
    const float* omp = omw + p * OMC;
    const int cgo = cg * 8;

    f32x4 acc[4] = {};

    const int tstart = kw * 5;
    const int tcount = 5 - kw;

    #pragma unroll
    for (int tt = 0; tt < 5; ++tt) {
        if (tt >= tcount) break;
        const int t = tstart + tt;
        const float py  = omp[2 * t];
        const float pxx = omp[2 * t + 1];
        const float mk  = omp[18 + t];

        const float fy = floorf(py), fx = floorf(pxx);
        const int y0 = (int)fy, x0 = (int)fx;
        const float wy1 = py - fy, wx1 = pxx - fx;
        const float wy0 = 1.0f - wy1, wx0 = 1.0f - wx1;
        const bool vy0 = (unsigned)y0 < (unsigned)HH;
        const bool vy1 = (unsigned)(y0 + 1) < (unsigned)HH;
        const bool vx0 = (unsigned)x0 < (unsigned)WW;
        const bool vx1 = (unsigned)(x0 + 1) < (unsigned)WW;
        const float w00 = (vy0 && vx0) ? wy0 * wx0 * mk : 0.0f;
        const float w01 = (vy0 && vx1) ? wy0 * wx1 * mk : 0.0f;
        const float w10 = (vy1 && vx0) ? wy1 * wx0 * mk : 0.0f;
        const float w11 = (vy1 && vx1) ? wy1 * wx1 * mk : 0.0f;
        const int yc0 = min(max(y0, 0), HH - 1);
        const int yc1 = min(max(y0 + 1, 0), HH - 1);
        const int xc0 = min(max(x0, 0), WW - 1);
        const int xc1 = min(max(x0 + 1, 0), WW - 1);

        const float* r00 = xb + (yc0 * WW + xc0) * CIN + cgo;
        const float* r01 = xb + (yc0 * WW + xc1) * CIN + cgo;
        const float* r10 = xb + (yc1 * WW + xc0) * CIN + cgo;
        const float* r11 = xb + (yc1 * WW + xc1) * CIN + cgo;

        float4 v00a = *(const float4*)(r00);      float4 v00b = *(const float4*)(r00 + 4);
        float4 v00c = *(const float4*)(r00 + 32); float4 v00d = *(const float4*)(r00 + 36);
        float4 v01a = *(const float4*)(r01);      float4 v01b = *(const float4*)(r01 + 4);
        float4 v01c = *(const float4*)(r01 + 32); float4 v01d = *(const float4*)(r01 + 36);
        float4 v10a = *(const float4*)(r10);      float4 v10b = *(const float4*)(r10 + 4);
        float4 v10c = *(const float4*)(r10 + 32); float4 v10d = *(const float4*)(r10 + 36);
        float4 v11a = *(const float4*)(r11);      float4 v11b = *(const float4*)(r11 + 4);
        float4 v11c = *(const float4*)(r11 + 32); float4 v11d = *(const float4*)(r11 + 36);

        float s[16];
        #pragma unroll
        for (int j = 0; j < 4; ++j) {
            s[j]      = w00 * ((const float*)&v00a)[j] + w01 * ((const float*)&v01a)[j]
                      + w10 * ((const float*)&v10a)[j] + w11 * ((const float*)&v11a)[j];
            s[4 + j]  = w00 * ((const float*)&v00b)[j] + w01 * ((const float*)&v01b)[j]
                      + w10 * ((const float*)&v10b)[j] + w11 * ((const float*)&v11b)[j];
            s[8 + j]  = w00 * ((const float*)&v00c)[j] + w01 * ((const float*)&v01c)[j]
                      + w10 * ((const float*)&v10c)[j] + w11 * ((const float*)&v11c)[j];
            s[12 + j] = w00 * ((const float*)&v00d)[j] + w01 * ((const float*)&v01d)[j]
                      + w10 * ((const float*)&v10d)[j] + w11 * ((const float*)&v11d)[j];
        }

        uint4 a0q, a1q;
        a0q.x = pk2(s[0],  s[1]);  a0q.y = pk2(s[2],  s[3]);
        a0q.z = pk2(s[4],  s[5]);  a0q.w = pk2(s[6],  s[7]);
        a1q.x = pk2(s[8],  s[9]);  a1q.y = pk2(s[10], s[11]);
        a1q.z = pk2(s[12], s[13]); a1q.w = pk2(s[14], s[15]);
        const bf16x8 a0 = *(const bf16x8*)&a0q;
        const bf16x8 a1 = *(const bf16x8*)&a1q;

        const uint4* wb0 = wb + (t * 2) * 4 * 64 + lane;
        #pragma unroll
        for (int nf = 0; nf < 4; ++nf) {
            const bf16x8 bfr = *(const bf16x8*)(wb0 + nf * 64);
            acc[nf] = __builtin_amdgcn_mfma_f32_16x16x32_bf16(a0, bfr, acc[nf], 0, 0, 0);
        }
        #pragma unroll
        for (int nf = 0; nf < 4; ++nf) {
            const bf16x8 bfr = *(const bf16x8*)(wb0 + (4 + nf) * 64);
            acc[nf] = __builtin_amdgcn_mfma_f32_16x16x32_bf16(a1, bfr, acc[nf], 0, 0, 0);
        }
    }

    // ---- pair reduction: kw=1 writes partials, kw=0 adds + bias + stores ----
    if (kw == 1) {
        #pragma unroll
        for (int nf = 0; nf < 4; ++nf) red[pair][nf * 64 + lane] = acc[nf];
    }
    __syncthreads();
    if (kw == 0) {
        #pragma unroll
        for (int nf = 0; nf < 4; ++nf) {
            const f32x4 o = red[pair][nf * 64 + lane];
            const int n  = nf * 16 + (lane & 15);
            const float bs = bias[n];
            const int m0 = pair * 16 + ((lane >> 4) * 4);
            #pragma unroll
            for (int r = 0; r < 4; ++r) {
                out[(size_t)(pix0 + m0 + r) * COUT + n] = acc[nf][r] + o[r] + bs;
            }
        }
    }
}

extern "C" void kernel_launch(void* const* d_in, const int* in_sizes, int n_in,
                              void* d_out, int out_size, void* d_ws, size_t ws_size,
                              hipStream_t stream)
{
    const float* x     = (const float*)d_in[0];
    const float* wmain = (const float*)d_in[1];
    const float* bias  = (const float*)d_in[2];
    const float* wofs  = (const float*)d_in[3];
    const float* bofs  = (const float*)d_in[4];
    float* out = (float*)d_out;
    float* om  = (float*)d_ws;                                    // 7077888 B
    uint4* wb  = (uint4*)((char*)d_ws + (size_t)NPIX * OMC * 4);  // +73728 B

    wb_transform<<<72, 64, 0, stream>>>(wmain, wb);
    offset_conv_mfma<<<BB * HH, 256, 0, stream>>>(x, wofs, bofs, om);
    dcn_main_mfma<<<NPIX / TMB, 256, 0, stream>>>(x, wb, bias, om, out);
}

// Round 7
// 64.120 us; speedup vs baseline: 1.7438x; 1.7438x over previous
//
#include <hip/hip_runtime.h>
#include <math.h>

#define BB 4
#define HH 128
#define WW 128
#define CIN 64
#define COUT 64
#define KK 9
#define OMC 27
#define NPIX (BB * HH * WW)

typedef __attribute__((ext_vector_type(8))) short bf16x8;
typedef __attribute__((ext_vector_type(4))) float f32x4;

static __device__ __forceinline__ unsigned short f2bf(float f) {
    unsigned int u = __float_as_uint(f);
    unsigned int r = (u + 0x7fffu + ((u >> 16) & 1u)) >> 16;
    return (unsigned short)r;
}

static __device__ __forceinline__ unsigned int pk2(float a, float b) {
    return (unsigned int)f2bf(a) | ((unsigned int)f2bf(b) << 16);
}

// ---------------------------------------------------------------------------
// Kernel 0: one-shot transform of wmain f32 [576 k][64 n] into bf16 MFMA
// B-frag-ready layout (16B/lane coalesced loads in the main kernel).
// ---------------------------------------------------------------------------
__global__ __launch_bounds__(64) void wb_transform(
    const float* __restrict__ wmain, uint4* __restrict__ wb)
{
    const int tid  = blockIdx.x * 64 + threadIdx.x;  // [0, 18*4*64)
    const int lane = tid & 63;
    const int nf   = (tid >> 6) & 3;
    const int ks   = tid >> 8;
    const int k0   = ks * 32 + ((lane >> 4) * 8);
    const int n    = nf * 16 + (lane & 15);
    unsigned short v[8];
    #pragma unroll
    for (int j = 0; j < 8; ++j) v[j] = f2bf(wmain[(size_t)(k0 + j) * COUT + n]);
    uint4 q;
    q.x = (unsigned int)v[0] | ((unsigned int)v[1] << 16);
    q.y = (unsigned int)v[2] | ((unsigned int)v[3] << 16);
    q.z = (unsigned int)v[4] | ((unsigned int)v[5] << 16);
    q.w = (unsigned int)v[6] | ((unsigned int)v[7] << 16);
    wb[tid] = q;
}

// ---------------------------------------------------------------------------
// Kernel 1: offset/mask conv as bf16 MFMA implicit GEMM.  Epilogue fuses the
// deformable prep: j<18 -> absolute sampling coords, j>=18 -> sigmoid(mask).
// ---------------------------------------------------------------------------
__global__ __launch_bounds__(256) void offset_conv_mfma(
    const float* __restrict__ x,
    const float* __restrict__ wofs,
    const float* __restrict__ bofs,
    float* __restrict__ om)
{
    __shared__ char lds[16384 + 36864];
    char* xs = lds;
    char* ws = lds + 16384;

    const int tid  = threadIdx.x;
    const int lane = tid & 63;
    const int wv   = tid >> 6;
    const int bid = ((blockIdx.x & 7) << 6) + (blockIdx.x >> 3);  // XCD chunk
    const int b = bid >> 7;
    const int h = bid & (HH - 1);
    const float* xrow0 = x + (size_t)b * HH * WW * CIN;

    #pragma unroll
    for (int r = 0; r < 9; ++r) {
        const int t  = r;
        const int j  = (tid >> 3) & 31;
        const int c8 = tid & 7;
        unsigned short v[8];
        if (j < OMC) {
            const float* wp = wofs + ((size_t)t * CIN + c8 * 8) * OMC + j;
            #pragma unroll
            for (int i = 0; i < 8; ++i) v[i] = f2bf(wp[i * OMC]);
        } else {
            #pragma unroll
            for (int i = 0; i < 8; ++i) v[i] = 0;
        }
        uint4 q;
        q.x = (unsigned int)v[0] | ((unsigned int)v[1] << 16);
        q.y = (unsigned int)v[2] | ((unsigned int)v[3] << 16);
        q.z = (unsigned int)v[4] | ((unsigned int)v[5] << 16);
        q.w = (unsigned int)v[6] | ((unsigned int)v[7] << 16);
        const int off = (((t * 32 + j) * 128) + c8 * 16) ^ ((j & 7) << 4);
        *(uint4*)(ws + off) = q;
    }

    f32x4 acc[2][2] = {};
    const int w0 = wv * 32;

    for (int ty = 0; ty < 3; ++ty) {
        const int hy = h - 1 + ty;
        const bool vrow = (hy >= 0) && (hy < HH);
        __syncthreads();
        if (vrow) {
            const float* src = xrow0 + (size_t)hy * WW * CIN;
            #pragma unroll
            for (int r = 0; r < 4; ++r) {
                const int ch = tid + 256 * r;
                const int c8 = ch & 7;
                const int w  = ch >> 3;
                const float* p = src + (size_t)w * CIN + c8 * 8;
                float4 a0 = *(const float4*)p;
                float4 a1 = *(const float4*)(p + 4);
                uint4 q;
                q.x = pk2(a0.x, a0.y);
                q.y = pk2(a0.z, a0.w);
                q.z = pk2(a1.x, a1.y);
                q.w = pk2(a1.z, a1.w);
                const int off = (w * 128 + c8 * 16) ^ ((w & 7) << 4);
                *(uint4*)(xs + off) = q;
            }
        }
        __syncthreads();
        if (!vrow) continue;

        #pragma unroll
        for (int tx = 0; tx < 3; ++tx) {
            const int t = ty * 3 + tx;
            #pragma unroll
            for (int ch2 = 0; ch2 < 2; ++ch2) {
                bf16x8 bfr[2];
                #pragma unroll
                for (int nf = 0; nf < 2; ++nf) {
                    const int j = nf * 16 + (lane & 15);
                    const int off = (((t * 32 + j) * 128) + ch2 * 64 + ((lane >> 4) * 16))
                                    ^ ((j & 7) << 4);
                    bfr[nf] = *(const bf16x8*)(ws + off);
                }
                bf16x8 afr[2];
                #pragma unroll
                for (int m = 0; m < 2; ++m) {
                    const int wp = w0 + m * 16 + (lane & 15) + tx - 1;
                    const bool vv = (wp >= 0) && (wp < WW);
                    const int wc = vv ? wp : 0;
                    const int off = (wc * 128 + ch2 * 64 + ((lane >> 4) * 16))
                                    ^ ((wc & 7) << 4);
                    bf16x8 a = *(const bf16x8*)(xs + off);
                    if (!vv) a = (bf16x8)(short)0;
                    afr[m] = a;
                }
                acc[0][0] = __builtin_amdgcn_mfma_f32_16x16x32_bf16(afr[0], bfr[0], acc[0][0], 0, 0, 0);
                acc[0][1] = __builtin_amdgcn_mfma_f32_16x16x32_bf16(afr[0], bfr[1], acc[0][1], 0, 0, 0);
                acc[1][0] = __builtin_amdgcn_mfma_f32_16x16x32_bf16(afr[1], bfr[0], acc[1][0], 0, 0, 0);
                acc[1][1] = __builtin_amdgcn_mfma_f32_16x16x32_bf16(afr[1], bfr[1], acc[1][1], 0, 0, 0);
            }
        }
    }

    const int pixbase = (b * HH + h) * WW;
    #pragma unroll
    for (int nf = 0; nf < 2; ++nf) {
        const int j = nf * 16 + (lane & 15);
        if (j >= OMC) continue;
        const float bb = bofs[j];
        #pragma unroll
        for (int m = 0; m < 2; ++m) {
            const int row0 = w0 + m * 16 + ((lane >> 4) * 4);
            #pragma unroll
            for (int r = 0; r < 4; ++r) {
                float val = acc[m][nf][r] + bb;
                const int wpix = row0 + r;
                if (j < 18) {
                    const int t = j >> 1;
                    if ((j & 1) == 0) val += (float)(h - 1 + t / 3);     // absolute py
                    else              val += (float)(wpix - 1 + t % 3);  // absolute px
                } else {
                    val = 1.0f / (1.0f + __expf(-val));                  // sigmoid(mask)
                }
                om[(size_t)(pixbase + wpix) * OMC + j] = val;
            }
        }
    }
}

// ---------------------------------------------------------------------------
// Kernel 2: deformable sampling + MFMA.  Per-tap LDS-tile pipeline (the
// proven low-VGPR structure) with 2-way K-SPLIT across a wave pair.
// Block = 256 thr = 4 waves = 2 pairs; each pair owns 16 pixels.
// kw=0: taps 0-4, kw=1: taps 5-8; both gather into WAVE-PRIVATE swizzled
// [16 px][64 ch] bf16 tiles (no barrier in the loop), MFMA-accumulate,
// then pair-reduce through LDS (overlaid on the dead tiles, 2 barriers).
// Gather: quarter-wave per pixel, 4 ch/lane float4 corner loads (coalesced
// 256B per pixel-corner), OOB killed via zeroed bilinear weight.
// Grid 2048 blocks -> up to 32 waves/CU.
// ---------------------------------------------------------------------------
#define TMB 32   // pixels per block

__global__ __launch_bounds__(256, 8) void dcn_main_mfma(
    const float* __restrict__ x,
    const uint4* __restrict__ wb,
    const float* __restrict__ bias,
    const float* __restrict__ om,
    float* __restrict__ out)
{
    __shared__ char  ts[4][2048];     // 8192 B: wave-private [16px][64ch] bf16
    __shared__ float om_s[2][432];    // 3456 B: per-pair om slice

    const int tid  = threadIdx.x;
    const int lane = tid & 63;
    const int wv   = tid >> 6;
    const int pair = wv >> 1;
    const int kw   = wv & 1;
    const int bid  = ((blockIdx.x & 7) << 8) + (blockIdx.x >> 3);  // XCD chunk
    const int pix0 = bid * TMB;
    const int b    = pix0 >> 14;
    const float* xb = x + (size_t)b * HH * WW * CIN;

    // ---- stage pair's om slice (both waves write identical values) ----
    float* omw = om_s[pair];
    {
        const float* og = om + (size_t)(pix0 + pair * 16) * OMC;
        #pragma unroll
        for (int i = 0; i < 7; ++i) {
            const int idx = i * 64 + lane;
            if (idx < 432) omw[idx] = og[idx];
        }
    }

    char* tsw = ts[wv];
    const int plq = lane >> 4;          // pixel sub-index within gather iter
    const int ch0 = (lane & 15) * 4;    // 4 channels per lane
    const float* xbc = xb + ch0;

    f32x4 acc[4] = {};

    const int tstart = kw * 5;
    const int tend   = 5 + kw * 4;      // kw=0: [0,5)  kw=1: [5,9)

    for (int t = tstart; t < tend; ++t) {
        // ---- gather this tap: 4 iters x 4 pixels, 4 ch/lane ----
        #pragma unroll
        for (int it = 0; it < 4; ++it) {
            const int pl = it * 4 + plq;
            const float* omp = omw + pl * OMC;
            const float py  = omp[2 * t];
            const float pxx = omp[2 * t + 1];
            const float mk  = omp[18 + t];

            const float fy = floorf(py), fx = floorf(pxx);
            const int y0 = (int)fy, x0 = (int)fx;
            const float wy1 = py - fy, wx1 = pxx - fx;
            const float wy0 = 1.0f - wy1, wx0 = 1.0f - wx1;
            const bool vy0 = (unsigned)y0 < (unsigned)HH;
            const bool vy1 = (unsigned)(y0 + 1) < (unsigned)HH;
            const bool vx0 = (unsigned)x0 < (unsigned)WW;
            const bool vx1 = (unsigned)(x0 + 1) < (unsigned)WW;
            const float w00 = (vy0 && vx0) ? wy0 * wx0 * mk : 0.0f;
            const float w01 = (vy0 && vx1) ? wy0 * wx1 * mk : 0.0f;
            const float w10 = (vy1 && vx0) ? wy1 * wx0 * mk : 0.0f;
            const float w11 = (vy1 && vx1) ? wy1 * wx1 * mk : 0.0f;
            const int yc0 = min(max(y0, 0), HH - 1);
            const int yc1 = min(max(y0 + 1, 0), HH - 1);
            const int xc0 = min(max(x0, 0), WW - 1);
            const int xc1 = min(max(x0 + 1, 0), WW - 1);

            const float4 c00 = *(const float4*)(xbc + (yc0 * WW + xc0) * CIN);
            const float4 c01 = *(const float4*)(xbc + (yc0 * WW + xc1) * CIN);
            const float4 c10 = *(const float4*)(xbc + (yc1 * WW + xc0) * CIN);
            const float4 c11 = *(const float4*)(xbc + (yc1 * WW + xc1) * CIN);

            float s0 = w00 * c00.x + w01 * c01.x + w10 * c10.x + w11 * c11.x;
            float s1 = w00 * c00.y + w01 * c01.y + w10 * c10.y + w11 * c11.y;
            float s2 = w00 * c00.z + w01 * c01.z + w10 * c10.z + w11 * c11.z;
            float s3 = w00 * c00.w + w01 * c01.w + w10 * c10.w + w11 * c11.w;

            uint2 pkd;
            pkd.x = pk2(s0, s1);
            pkd.y = pk2(s2, s3);
            const int off = (pl * 128 + ch0 * 2) ^ ((pl & 7) << 4);
            *(uint2*)(tsw + off) = pkd;
        }

        // ---- 2 K-steps of MFMA on the fresh tap tile (wave-private) ----
        const int arow = lane & 15;
        const int aswz = (arow & 7) << 4;
        const uint4* wb0 = wb + (t * 2) * 4 * 64 + lane;
        #pragma unroll
        for (int ch2 = 0; ch2 < 2; ++ch2) {
            const bf16x8 a = *(const bf16x8*)(
                tsw + ((arow * 128 + ch2 * 64 + ((lane >> 4) * 16)) ^ aswz));
            #pragma unroll
            for (int nf = 0; nf < 4; ++nf) {
                const bf16x8 bfr = *(const bf16x8*)(wb0 + (ch2 * 4 + nf) * 64);
                acc[nf] = __builtin_amdgcn_mfma_f32_16x16x32_bf16(a, bfr, acc[nf], 0, 0, 0);
            }
        }
    }

    // ---- pair reduction: overlay red buffer on the (now dead) tiles ----
    __syncthreads();   // everyone done reading their tiles
    f32x4* red = (f32x4*)(ts[0]);      // 8192 B = 2 pairs x 64 lanes x 4 f32x4
    if (kw == 1) {
        #pragma unroll
        for (int nf = 0; nf < 4; ++nf) red[(pair * 4 + nf) * 64 + lane] = acc[nf];
    }
    __syncthreads();
    if (kw == 0) {
        #pragma unroll
        for (int nf = 0; nf < 4; ++nf) {
            const f32x4 o = red[(pair * 4 + nf) * 64 + lane];
            const int n  = nf * 16 + (lane & 15);
            const float bs = bias[n];
            const int m0 = pair * 16 + ((lane >> 4) * 4);
            #pragma unroll
            for (int r = 0; r < 4; ++r) {
                out[(size_t)(pix0 + m0 + r) * COUT + n] = acc[nf][r] + o[r] + bs;
            }
        }
    }
}

extern "C" void kernel_launch(void* const* d_in, const int* in_sizes, int n_in,
                              void* d_out, int out_size, void* d_ws, size_t ws_size,
                              hipStream_t stream)
{
    const float* x     = (const float*)d_in[0];
    const float* wmain = (const float*)d_in[1];
    const float* bias  = (const float*)d_in[2];
    const float* wofs  = (const float*)d_in[3];
    const float* bofs  = (const float*)d_in[4];
    float* out = (float*)d_out;
    float* om  = (float*)d_ws;                                    // 7077888 B
    uint4* wb  = (uint4*)((char*)d_ws + (size_t)NPIX * OMC * 4);  // +73728 B

    wb_transform<<<72, 64, 0, stream>>>(wmain, wb);
    offset_conv_mfma<<<BB * HH, 256, 0, stream>>>(x, wofs, bofs, om);
    dcn_main_mfma<<<NPIX / TMB, 256, 0, stream>>>(x, wb, bias, om, out);
}

// Round 8
// 59.158 us; speedup vs baseline: 1.8901x; 1.0839x over previous
//
#include <hip/hip_runtime.h>
#include <math.h>

#define BB 4
#define HH 128
#define WW 128
#define CIN 64
#define COUT 64
#define KK 9
#define OMC 27
#define NPIX (BB * HH * WW)

typedef __attribute__((ext_vector_type(8))) short bf16x8;
typedef __attribute__((ext_vector_type(4))) float f32x4;

static __device__ __forceinline__ unsigned short f2bf(float f) {
    unsigned int u = __float_as_uint(f);
    unsigned int r = (u + 0x7fffu + ((u >> 16) & 1u)) >> 16;
    return (unsigned short)r;
}

static __device__ __forceinline__ unsigned int pk2(float a, float b) {
    return (unsigned int)f2bf(a) | ((unsigned int)f2bf(b) << 16);
}

// ---------------------------------------------------------------------------
// Kernel 0: one-shot transform of wmain f32 [576 k][64 n] into bf16 MFMA
// B-frag-ready layout (16B/lane coalesced loads in the main kernel).
// ---------------------------------------------------------------------------
__global__ __launch_bounds__(64) void wb_transform(
    const float* __restrict__ wmain, uint4* __restrict__ wb)
{
    const int tid  = blockIdx.x * 64 + threadIdx.x;  // [0, 18*4*64)
    const int lane = tid & 63;
    const int nf   = (tid >> 6) & 3;
    const int ks   = tid >> 8;
    const int k0   = ks * 32 + ((lane >> 4) * 8);
    const int n    = nf * 16 + (lane & 15);
    unsigned short v[8];
    #pragma unroll
    for (int j = 0; j < 8; ++j) v[j] = f2bf(wmain[(size_t)(k0 + j) * COUT + n]);
    uint4 q;
    q.x = (unsigned int)v[0] | ((unsigned int)v[1] << 16);
    q.y = (unsigned int)v[2] | ((unsigned int)v[3] << 16);
    q.z = (unsigned int)v[4] | ((unsigned int)v[5] << 16);
    q.w = (unsigned int)v[6] | ((unsigned int)v[7] << 16);
    wb[tid] = q;
}

// ---------------------------------------------------------------------------
// Kernel 1: offset/mask conv as bf16 MFMA implicit GEMM.  Epilogue fuses the
// deformable prep: j<18 -> absolute sampling coords, j>=18 -> sigmoid(mask).
// ---------------------------------------------------------------------------
__global__ __launch_bounds__(256) void offset_conv_mfma(
    const float* __restrict__ x,
    const float* __restrict__ wofs,
    const float* __restrict__ bofs,
    float* __restrict__ om)
{
    __shared__ char lds[16384 + 36864];
    char* xs = lds;
    char* ws = lds + 16384;

    const int tid  = threadIdx.x;
    const int lane = tid & 63;
    const int wv   = tid >> 6;
    const int bid = ((blockIdx.x & 7) << 6) + (blockIdx.x >> 3);  // XCD chunk
    const int b = bid >> 7;
    const int h = bid & (HH - 1);
    const float* xrow0 = x + (size_t)b * HH * WW * CIN;

    #pragma unroll
    for (int r = 0; r < 9; ++r) {
        const int t  = r;
        const int j  = (tid >> 3) & 31;
        const int c8 = tid & 7;
        unsigned short v[8];
        if (j < OMC) {
            const float* wp = wofs + ((size_t)t * CIN + c8 * 8) * OMC + j;
            #pragma unroll
            for (int i = 0; i < 8; ++i) v[i] = f2bf(wp[i * OMC]);
        } else {
            #pragma unroll
            for (int i = 0; i < 8; ++i) v[i] = 0;
        }
        uint4 q;
        q.x = (unsigned int)v[0] | ((unsigned int)v[1] << 16);
        q.y = (unsigned int)v[2] | ((unsigned int)v[3] << 16);
        q.z = (unsigned int)v[4] | ((unsigned int)v[5] << 16);
        q.w = (unsigned int)v[6] | ((unsigned int)v[7] << 16);
        const int off = (((t * 32 + j) * 128) + c8 * 16) ^ ((j & 7) << 4);
        *(uint4*)(ws + off) = q;
    }

    f32x4 acc[2][2] = {};
    const int w0 = wv * 32;

    for (int ty = 0; ty < 3; ++ty) {
        const int hy = h - 1 + ty;
        const bool vrow = (hy >= 0) && (hy < HH);
        __syncthreads();
        if (vrow) {
            const float* src = xrow0 + (size_t)hy * WW * CIN;
            #pragma unroll
            for (int r = 0; r < 4; ++r) {
                const int ch = tid + 256 * r;
                const int c8 = ch & 7;
                const int w  = ch >> 3;
                const float* p = src + (size_t)w * CIN + c8 * 8;
                float4 a0 = *(const float4*)p;
                float4 a1 = *(const float4*)(p + 4);
                uint4 q;
                q.x = pk2(a0.x, a0.y);
                q.y = pk2(a0.z, a0.w);
                q.z = pk2(a1.x, a1.y);
                q.w = pk2(a1.z, a1.w);
                const int off = (w * 128 + c8 * 16) ^ ((w & 7) << 4);
                *(uint4*)(xs + off) = q;
            }
        }
        __syncthreads();
        if (!vrow) continue;

        #pragma unroll
        for (int tx = 0; tx < 3; ++tx) {
            const int t = ty * 3 + tx;
            #pragma unroll
            for (int ch2 = 0; ch2 < 2; ++ch2) {
                bf16x8 bfr[2];
                #pragma unroll
                for (int nf = 0; nf < 2; ++nf) {
                    const int j = nf * 16 + (lane & 15);
                    const int off = (((t * 32 + j) * 128) + ch2 * 64 + ((lane >> 4) * 16))
                                    ^ ((j & 7) << 4);
                    bfr[nf] = *(const bf16x8*)(ws + off);
                }
                bf16x8 afr[2];
                #pragma unroll
                for (int m = 0; m < 2; ++m) {
                    const int wp = w0 + m * 16 + (lane & 15) + tx - 1;
                    const bool vv = (wp >= 0) && (wp < WW);
                    const int wc = vv ? wp : 0;
                    const int off = (wc * 128 + ch2 * 64 + ((lane >> 4) * 16))
                                    ^ ((wc & 7) << 4);
                    bf16x8 a = *(const bf16x8*)(xs + off);
                    if (!vv) a = (bf16x8)(short)0;
                    afr[m] = a;
                }
                acc[0][0] = __builtin_amdgcn_mfma_f32_16x16x32_bf16(afr[0], bfr[0], acc[0][0], 0, 0, 0);
                acc[0][1] = __builtin_amdgcn_mfma_f32_16x16x32_bf16(afr[0], bfr[1], acc[0][1], 0, 0, 0);
                acc[1][0] = __builtin_amdgcn_mfma_f32_16x16x32_bf16(afr[1], bfr[0], acc[1][0], 0, 0, 0);
                acc[1][1] = __builtin_amdgcn_mfma_f32_16x16x32_bf16(afr[1], bfr[1], acc[1][1], 0, 0, 0);
            }
        }
    }

    const int pixbase = (b * HH + h) * WW;
    #pragma unroll
    for (int nf = 0; nf < 2; ++nf) {
        const int j = nf * 16 + (lane & 15);
        if (j >= OMC) continue;
        const float bb = bofs[j];
        #pragma unroll
        for (int m = 0; m < 2; ++m) {
            const int row0 = w0 + m * 16 + ((lane >> 4) * 4);
            #pragma unroll
            for (int r = 0; r < 4; ++r) {
                float val = acc[m][nf][r] + bb;
                const int wpix = row0 + r;
                if (j < 18) {
                    const int t = j >> 1;
                    if ((j & 1) == 0) val += (float)(h - 1 + t / 3);     // absolute py
                    else              val += (float)(wpix - 1 + t % 3);  // absolute px
                } else {
                    val = 1.0f / (1.0f + __expf(-val));                  // sigmoid(mask)
                }
                om[(size_t)(pixbase + wpix) * OMC + j] = val;
            }
        }
    }
}

// ---------------------------------------------------------------------------
// Kernel 2: deformable sampling + MFMA.  Per-tap LDS-tile pipeline with
// 2-way K-SPLIT across a wave pair.  Identical to round 7 except
// __launch_bounds__(256, 6): the (256,8) 64-VGPR cap caused ~22 MB of
// scratch spill (WRITE_SIZE 38.9 MB vs 16.7 MB ideal); 84 VGPRs fits the
// unrolled gather's live set while still allowing 24 waves/CU (achieved
// occupancy was ~21 waves/CU anyway).
// ---------------------------------------------------------------------------
#define TMB 32   // pixels per block

__global__ __launch_bounds__(256, 6) void dcn_main_mfma(
    const float* __restrict__ x,
    const uint4* __restrict__ wb,
    const float* __restrict__ bias,
    const float* __restrict__ om,
    float* __restrict__ out)
{
    __shared__ char  ts[4][2048];     // 8192 B: wave-private [16px][64ch] bf16
    __shared__ float om_s[2][432];    // 3456 B: per-pair om slice

    const int tid  = threadIdx.x;
    const int lane = tid & 63;
    const int wv   = tid >> 6;
    const int pair = wv >> 1;
    const int kw   = wv & 1;
    const int bid  = ((blockIdx.x & 7) << 8) + (blockIdx.x >> 3);  // XCD chunk
    const int pix0 = bid * TMB;
    const int b    = pix0 >> 14;
    const float* xb = x + (size_t)b * HH * WW * CIN;

    // ---- stage pair's om slice (both waves write identical values) ----
    float* omw = om_s[pair];
    {
        const float* og = om + (size_t)(pix0 + pair * 16) * OMC;
        #pragma unroll
        for (int i = 0; i < 7; ++i) {
            const int idx = i * 64 + lane;
            if (idx < 432) omw[idx] = og[idx];
        }
    }

    char* tsw = ts[wv];
    const int plq = lane >> 4;          // pixel sub-index within gather iter
    const int ch0 = (lane & 15) * 4;    // 4 channels per lane
    const float* xbc = xb + ch0;

    f32x4 acc[4] = {};

    const int tstart = kw * 5;
    const int tend   = 5 + kw * 4;      // kw=0: [0,5)  kw=1: [5,9)

    for (int t = tstart; t < tend; ++t) {
        // ---- gather this tap: 4 iters x 4 pixels, 4 ch/lane ----
        #pragma unroll
        for (int it = 0; it < 4; ++it) {
            const int pl = it * 4 + plq;
            const float* omp = omw + pl * OMC;
            const float py  = omp[2 * t];
            const float pxx = omp[2 * t + 1];
            const float mk  = omp[18 + t];

            const float fy = floorf(py), fx = floorf(pxx);
            const int y0 = (int)fy, x0 = (int)fx;
            const float wy1 = py - fy, wx1 = pxx - fx;
            const float wy0 = 1.0f - wy1, wx0 = 1.0f - wx1;
            const bool vy0 = (unsigned)y0 < (unsigned)HH;
            const bool vy1 = (unsigned)(y0 + 1) < (unsigned)HH;
            const bool vx0 = (unsigned)x0 < (unsigned)WW;
            const bool vx1 = (unsigned)(x0 + 1) < (unsigned)WW;
            const float w00 = (vy0 && vx0) ? wy0 * wx0 * mk : 0.0f;
            const float w01 = (vy0 && vx1) ? wy0 * wx1 * mk : 0.0f;
            const float w10 = (vy1 && vx0) ? wy1 * wx0 * mk : 0.0f;
            const float w11 = (vy1 && vx1) ? wy1 * wx1 * mk : 0.0f;
            const int yc0 = min(max(y0, 0), HH - 1);
            const int yc1 = min(max(y0 + 1, 0), HH - 1);
            const int xc0 = min(max(x0, 0), WW - 1);
            const int xc1 = min(max(x0 + 1, 0), WW - 1);

            const float4 c00 = *(const float4*)(xbc + (yc0 * WW + xc0) * CIN);
            const float4 c01 = *(const float4*)(xbc + (yc0 * WW + xc1) * CIN);
            const float4 c10 = *(const float4*)(xbc + (yc1 * WW + xc0) * CIN);
            const float4 c11 = *(const float4*)(xbc + (yc1 * WW + xc1) * CIN);

            float s0 = w00 * c00.x + w01 * c01.x + w10 * c10.x + w11 * c11.x;
            float s1 = w00 * c00.y + w01 * c01.y + w10 * c10.y + w11 * c11.y;
            float s2 = w00 * c00.z + w01 * c01.z + w10 * c10.z + w11 * c11.z;
            float s3 = w00 * c00.w + w01 * c01.w + w10 * c10.w + w11 * c11.w;

            uint2 pkd;
            pkd.x = pk2(s0, s1);
            pkd.y = pk2(s2, s3);
            const int off = (pl * 128 + ch0 * 2) ^ ((pl & 7) << 4);
            *(uint2*)(tsw + off) = pkd;
        }

        // ---- 2 K-steps of MFMA on the fresh tap tile (wave-private) ----
        const int arow = lane & 15;
        const int aswz = (arow & 7) << 4;
        const uint4* wb0 = wb + (t * 2) * 4 * 64 + lane;
        #pragma unroll
        for (int ch2 = 0; ch2 < 2; ++ch2) {
            const bf16x8 a = *(const bf16x8*)(
                tsw + ((arow * 128 + ch2 * 64 + ((lane >> 4) * 16)) ^ aswz));
            #pragma unroll
            for (int nf = 0; nf < 4; ++nf) {
                const bf16x8 bfr = *(const bf16x8*)(wb0 + (ch2 * 4 + nf) * 64);
                acc[nf] = __builtin_amdgcn_mfma_f32_16x16x32_bf16(a, bfr, acc[nf], 0, 0, 0);
            }
        }
    }

    // ---- pair reduction: overlay red buffer on the (now dead) tiles ----
    __syncthreads();   // everyone done reading their tiles
    f32x4* red = (f32x4*)(ts[0]);      // 8192 B = 2 pairs x 64 lanes x 4 f32x4
    if (kw == 1) {
        #pragma unroll
        for (int nf = 0; nf < 4; ++nf) red[(pair * 4 + nf) * 64 + lane] = acc[nf];
    }
    __syncthreads();
    if (kw == 0) {
        #pragma unroll
        for (int nf = 0; nf < 4; ++nf) {
            const f32x4 o = red[(pair * 4 + nf) * 64 + lane];
            const int n  = nf * 16 + (lane & 15);
            const float bs = bias[n];
            const int m0 = pair * 16 + ((lane >> 4) * 4);
            #pragma unroll
            for (int r = 0; r < 4; ++r) {
                out[(size_t)(pix0 + m0 + r) * COUT + n] = acc[nf][r] + o[r] + bs;
            }
        }
    }
}

extern "C" void kernel_launch(void* const* d_in, const int* in_sizes, int n_in,
                              void* d_out, int out_size, void* d_ws, size_t ws_size,
                              hipStream_t stream)
{
    const float* x     = (const float*)d_in[0];
    const float* wmain = (const float*)d_in[1];
    const float* bias  = (const float*)d_in[2];
    const float* wofs  = (const float*)d_in[3];
    const float* bofs  = (const float*)d_in[4];
    float* out = (float*)d_out;
    float* om  = (float*)d_ws;                                    // 7077888 B
    uint4* wb  = (uint4*)((char*)d_ws + (size_t)NPIX * OMC * 4);  // +73728 B

    wb_transform<<<72, 64, 0, stream>>>(wmain, wb);
    offset_conv_mfma<<<BB * HH, 256, 0, stream>>>(x, wofs, bofs, om);
    dcn_main_mfma<<<NPIX / TMB, 256, 0, stream>>>(x, wb, bias, om, out);
}

// Round 9
// 58.859 us; speedup vs baseline: 1.8997x; 1.0051x over previous
//
#include <hip/hip_runtime.h>
#include <hip/hip_bf16.h>
#include <math.h>

#define BB 4
#define HH 128
#define WW 128
#define CIN 64
#define COUT 64
#define KK 9
#define OMC 27
#define NPIX (BB * HH * WW)

typedef __attribute__((ext_vector_type(8))) short bf16x8;
typedef __attribute__((ext_vector_type(4))) float f32x4;

static __device__ __forceinline__ unsigned int pkcvt(float a, float b) {
    __hip_bfloat162 h = __float22bfloat162_rn(make_float2(a, b));
    return *reinterpret_cast<unsigned int*>(&h);
}

// ---------------------------------------------------------------------------
// Kernel 0: one-shot transform of wmain f32 [576 k][64 n] into bf16 MFMA
// B-frag-ready layout (16B/lane coalesced loads in the main kernel).
// ---------------------------------------------------------------------------
__global__ __launch_bounds__(64) void wb_transform(
    const float* __restrict__ wmain, uint4* __restrict__ wb)
{
    const int tid  = blockIdx.x * 64 + threadIdx.x;  // [0, 18*4*64)
    const int lane = tid & 63;
    const int nf   = (tid >> 6) & 3;
    const int ks   = tid >> 8;
    const int k0   = ks * 32 + ((lane >> 4) * 8);
    const int n    = nf * 16 + (lane & 15);
    uint4 q;
    q.x = pkcvt(wmain[(size_t)(k0 + 0) * COUT + n], wmain[(size_t)(k0 + 1) * COUT + n]);
    q.y = pkcvt(wmain[(size_t)(k0 + 2) * COUT + n], wmain[(size_t)(k0 + 3) * COUT + n]);
    q.z = pkcvt(wmain[(size_t)(k0 + 4) * COUT + n], wmain[(size_t)(k0 + 5) * COUT + n]);
    q.w = pkcvt(wmain[(size_t)(k0 + 6) * COUT + n], wmain[(size_t)(k0 + 7) * COUT + n]);
    wb[tid] = q;
}

// ---------------------------------------------------------------------------
// Kernel 1: offset/mask conv as bf16 MFMA implicit GEMM.  Epilogue fuses the
// deformable prep: j<18 -> absolute sampling coords, j>=18 -> sigmoid(mask).
// ---------------------------------------------------------------------------
__global__ __launch_bounds__(256) void offset_conv_mfma(
    const float* __restrict__ x,
    const float* __restrict__ wofs,
    const float* __restrict__ bofs,
    float* __restrict__ om)
{
    __shared__ char lds[16384 + 36864];
    char* xs = lds;
    char* ws = lds + 16384;

    const int tid  = threadIdx.x;
    const int lane = tid & 63;
    const int wv   = tid >> 6;
    const int bid = ((blockIdx.x & 7) << 6) + (blockIdx.x >> 3);  // XCD chunk
    const int b = bid >> 7;
    const int h = bid & (HH - 1);
    const float* xrow0 = x + (size_t)b * HH * WW * CIN;

    #pragma unroll
    for (int r = 0; r < 9; ++r) {
        const int t  = r;
        const int j  = (tid >> 3) & 31;
        const int c8 = tid & 7;
        uint4 q;
        if (j < OMC) {
            const float* wp = wofs + ((size_t)t * CIN + c8 * 8) * OMC + j;
            q.x = pkcvt(wp[0 * OMC], wp[1 * OMC]);
            q.y = pkcvt(wp[2 * OMC], wp[3 * OMC]);
            q.z = pkcvt(wp[4 * OMC], wp[5 * OMC]);
            q.w = pkcvt(wp[6 * OMC], wp[7 * OMC]);
        } else {
            q.x = q.y = q.z = q.w = 0u;
        }
        const int off = (((t * 32 + j) * 128) + c8 * 16) ^ ((j & 7) << 4);
        *(uint4*)(ws + off) = q;
    }

    f32x4 acc[2][2] = {};
    const int w0 = wv * 32;

    for (int ty = 0; ty < 3; ++ty) {
        const int hy = h - 1 + ty;
        const bool vrow = (hy >= 0) && (hy < HH);
        __syncthreads();
        if (vrow) {
            const float* src = xrow0 + (size_t)hy * WW * CIN;
            #pragma unroll
            for (int r = 0; r < 4; ++r) {
                const int ch = tid + 256 * r;
                const int c8 = ch & 7;
                const int w  = ch >> 3;
                const float* p = src + (size_t)w * CIN + c8 * 8;
                float4 a0 = *(const float4*)p;
                float4 a1 = *(const float4*)(p + 4);
                uint4 q;
                q.x = pkcvt(a0.x, a0.y);
                q.y = pkcvt(a0.z, a0.w);
                q.z = pkcvt(a1.x, a1.y);
                q.w = pkcvt(a1.z, a1.w);
                const int off = (w * 128 + c8 * 16) ^ ((w & 7) << 4);
                *(uint4*)(xs + off) = q;
            }
        }
        __syncthreads();
        if (!vrow) continue;

        #pragma unroll
        for (int tx = 0; tx < 3; ++tx) {
            const int t = ty * 3 + tx;
            #pragma unroll
            for (int ch2 = 0; ch2 < 2; ++ch2) {
                bf16x8 bfr[2];
                #pragma unroll
                for (int nf = 0; nf < 2; ++nf) {
                    const int j = nf * 16 + (lane & 15);
                    const int off = (((t * 32 + j) * 128) + ch2 * 64 + ((lane >> 4) * 16))
                                    ^ ((j & 7) << 4);
                    bfr[nf] = *(const bf16x8*)(ws + off);
                }
                bf16x8 afr[2];
                #pragma unroll
                for (int m = 0; m < 2; ++m) {
                    const int wp = w0 + m * 16 + (lane & 15) + tx - 1;
                    const bool vv = (wp >= 0) && (wp < WW);
                    const int wc = vv ? wp : 0;
                    const int off = (wc * 128 + ch2 * 64 + ((lane >> 4) * 16))
                                    ^ ((wc & 7) << 4);
                    bf16x8 a = *(const bf16x8*)(xs + off);
                    if (!vv) a = (bf16x8)(short)0;
                    afr[m] = a;
                }
                acc[0][0] = __builtin_amdgcn_mfma_f32_16x16x32_bf16(afr[0], bfr[0], acc[0][0], 0, 0, 0);
                acc[0][1] = __builtin_amdgcn_mfma_f32_16x16x32_bf16(afr[0], bfr[1], acc[0][1], 0, 0, 0);
                acc[1][0] = __builtin_amdgcn_mfma_f32_16x16x32_bf16(afr[1], bfr[0], acc[1][0], 0, 0, 0);
                acc[1][1] = __builtin_amdgcn_mfma_f32_16x16x32_bf16(afr[1], bfr[1], acc[1][1], 0, 0, 0);
            }
        }
    }

    const int pixbase = (b * HH + h) * WW;
    #pragma unroll
    for (int nf = 0; nf < 2; ++nf) {
        const int j = nf * 16 + (lane & 15);
        if (j >= OMC) continue;
        const float bb = bofs[j];
        #pragma unroll
        for (int m = 0; m < 2; ++m) {
            const int row0 = w0 + m * 16 + ((lane >> 4) * 4);
            #pragma unroll
            for (int r = 0; r < 4; ++r) {
                float val = acc[m][nf][r] + bb;
                const int wpix = row0 + r;
                if (j < 18) {
                    const int t = j >> 1;
                    if ((j & 1) == 0) val += (float)(h - 1 + t / 3);     // absolute py
                    else              val += (float)(wpix - 1 + t % 3);  // absolute px
                } else {
                    val = 1.0f / (1.0f + __expf(-val));                  // sigmoid(mask)
                }
                om[(size_t)(pixbase + wpix) * OMC + j] = val;
            }
        }
    }
}

// ---------------------------------------------------------------------------
// Kernel 2: deformable sampling + MFMA.
// Block = 256 thr = 4 waves = 2 pairs; each pair owns 16 pixels.
// PRECOMPUTE: all 256 threads build 288 (pixel,tap) entries ONCE:
//   {4 mask-folded bilinear weights, 4 clamped corner byte-offsets} -> LDS.
//   (Removes the 16x-redundant coord chain from the hot loop.)
// K-SPLIT by channel half: wave kw handles ch [kw*32, kw*32+32) of ALL 9
//   taps -> 18 identical gather iters per wave, perfectly balanced, tiles
//   stay wave-private (1 KB) -> no in-loop barriers.
// Gather iter: 2 LDS entry broadcasts + 4 coalesced float4 corner loads
//   (8 lanes x 16B = 128B per pixel-corner) + 16 FMA + cvt_pk pack.
// MFMA: ks = t*2+kw; A from swizzled private tile, B coalesced from wb/L2.
// Pair-reduce acc through LDS (overlaid on dead entry buffer, 2 barriers).
// ---------------------------------------------------------------------------
#define TMB 32   // pixels per block

__global__ __launch_bounds__(256, 6) void dcn_main_mfma(
    const float* __restrict__ x,
    const uint4* __restrict__ wb,
    const float* __restrict__ bias,
    const float* __restrict__ om,
    float* __restrict__ out)
{
    __shared__ char shm[9216 + 4096];
    float4* ent_w = (float4*)shm;            // 288 * 16 = 4608 B
    int4*   ent_o = (int4*)(shm + 4608);     // 288 * 16 = 4608 B
    char*   ts    = shm + 9216;              // 4 waves * 1024 B tiles

    const int tid  = threadIdx.x;
    const int lane = tid & 63;
    const int wv   = tid >> 6;
    const int pair = wv >> 1;
    const int kw   = wv & 1;                 // channel half
    const int bid  = ((blockIdx.x & 7) << 8) + (blockIdx.x >> 3);  // XCD chunk
    const int pix0 = bid * TMB;
    const int b    = pix0 >> 14;
    const float* xb = x + (size_t)b * HH * WW * CIN;

    // ---- precompute 288 (pixel,tap) entries ----
    for (int e = tid; e < 288; e += 256) {
        const int pr = e / 144;
        const int r  = e - pr * 144;
        const int px = r / 9;
        const int t  = r - px * 9;
        const float* omp = om + (size_t)(pix0 + pr * 16 + px) * OMC;
        const float py  = omp[2 * t];
        const float pxx = omp[2 * t + 1];
        const float mk  = omp[18 + t];

        const float fy = floorf(py), fx = floorf(pxx);
        const int y0 = (int)fy, x0 = (int)fx;
        const float wy1 = py - fy, wx1 = pxx - fx;
        const float wy0 = 1.0f - wy1, wx0 = 1.0f - wx1;
        const bool vy0 = (unsigned)y0 < (unsigned)HH;
        const bool vy1 = (unsigned)(y0 + 1) < (unsigned)HH;
        const bool vx0 = (unsigned)x0 < (unsigned)WW;
        const bool vx1 = (unsigned)(x0 + 1) < (unsigned)WW;
        float4 w4;
        w4.x = (vy0 && vx0) ? wy0 * wx0 * mk : 0.0f;
        w4.y = (vy0 && vx1) ? wy0 * wx1 * mk : 0.0f;
        w4.z = (vy1 && vx0) ? wy1 * wx0 * mk : 0.0f;
        w4.w = (vy1 && vx1) ? wy1 * wx1 * mk : 0.0f;
        const int yc0 = min(max(y0, 0), HH - 1);
        const int yc1 = min(max(y0 + 1, 0), HH - 1);
        const int xc0 = min(max(x0, 0), WW - 1);
        const int xc1 = min(max(x0 + 1, 0), WW - 1);
        int4 o4;
        o4.x = (yc0 * WW + xc0) * (CIN * 4);
        o4.y = (yc0 * WW + xc1) * (CIN * 4);
        o4.z = (yc1 * WW + xc0) * (CIN * 4);
        o4.w = (yc1 * WW + xc1) * (CIN * 4);
        ent_w[e] = w4;
        ent_o[e] = o4;
    }
    __syncthreads();

    char* tsw = ts + wv * 1024;
    const char* xc = (const char*)xb + (size_t)(kw * 32 + (lane & 7) * 4) * 4;
    const int ebase = pair * 144;

    f32x4 acc[4] = {};

    for (int t = 0; t < KK; ++t) {
        // ---- gather: 2 iters x 8 pixels, 4 ch/lane (within kw half) ----
        #pragma unroll
        for (int it = 0; it < 2; ++it) {
            const int px = it * 8 + (lane >> 3);
            const int e  = ebase + px * 9 + t;
            const float4 w4 = ent_w[e];
            const int4   o4 = ent_o[e];

            const float4 c00 = *(const float4*)(xc + o4.x);
            const float4 c01 = *(const float4*)(xc + o4.y);
            const float4 c10 = *(const float4*)(xc + o4.z);
            const float4 c11 = *(const float4*)(xc + o4.w);

            const float s0 = w4.x * c00.x + w4.y * c01.x + w4.z * c10.x + w4.w * c11.x;
            const float s1 = w4.x * c00.y + w4.y * c01.y + w4.z * c10.y + w4.w * c11.y;
            const float s2 = w4.x * c00.z + w4.y * c01.z + w4.z * c10.z + w4.w * c11.z;
            const float s3 = w4.x * c00.w + w4.y * c01.w + w4.z * c10.w + w4.w * c11.w;

            uint2 pkd;
            pkd.x = pkcvt(s0, s1);
            pkd.y = pkcvt(s2, s3);
            const int off = px * 64 + (((lane & 7) * 8) ^ ((px & 3) << 4));
            *(uint2*)(tsw + off) = pkd;
        }

        // ---- 1 K-step of MFMA on this wave's 32-ch half ----
        const int row = lane & 15;
        const int aoff = row * 64 + ((((lane >> 4) * 16)) ^ ((row & 3) << 4));
        const bf16x8 a = *(const bf16x8*)(tsw + aoff);
        const int ks = t * 2 + kw;
        const uint4* wb0 = wb + ks * 4 * 64 + lane;
        #pragma unroll
        for (int nf = 0; nf < 4; ++nf) {
            const bf16x8 bfr = *(const bf16x8*)(wb0 + nf * 64);
            acc[nf] = __builtin_amdgcn_mfma_f32_16x16x32_bf16(a, bfr, acc[nf], 0, 0, 0);
        }
    }

    // ---- pair reduction: overlay red buffer on the dead entry arrays ----
    __syncthreads();                      // all waves done with entries/tiles
    f32x4* red = (f32x4*)shm;             // 2 pairs x 4 nf x 64 lanes x 16B = 8192 B
    if (kw == 1) {
        #pragma unroll
        for (int nf = 0; nf < 4; ++nf) red[(pair * 4 + nf) * 64 + lane] = acc[nf];
    }
    __syncthreads();
    if (kw == 0) {
        #pragma unroll
        for (int nf = 0; nf < 4; ++nf) {
            const f32x4 o = red[(pair * 4 + nf) * 64 + lane];
            const int n  = nf * 16 + (lane & 15);
            const float bs = bias[n];
            const int m0 = pair * 16 + ((lane >> 4) * 4);
            #pragma unroll
            for (int r = 0; r < 4; ++r) {
                out[(size_t)(pix0 + m0 + r) * COUT + n] = acc[nf][r] + o[r] + bs;
            }
        }
    }
}

extern "C" void kernel_launch(void* const* d_in, const int* in_sizes, int n_in,
                              void* d_out, int out_size, void* d_ws, size_t ws_size,
                              hipStream_t stream)
{
    const float* x     = (const float*)d_in[0];
    const float* wmain = (const float*)d_in[1];
    const float* bias  = (const float*)d_in[2];
    const float* wofs  = (const float*)d_in[3];
    const float* bofs  = (const float*)d_in[4];
    float* out = (float*)d_out;
    float* om  = (float*)d_ws;                                    // 7077888 B
    uint4* wb  = (uint4*)((char*)d_ws + (size_t)NPIX * OMC * 4);  // +73728 B

    wb_transform<<<72, 64, 0, stream>>>(wmain, wb);
    offset_conv_mfma<<<BB * HH, 256, 0, stream>>>(x, wofs, bofs, om);
    dcn_main_mfma<<<NPIX / TMB, 256, 0, stream>>>(x, wb, bias, om, out);
}